// Round 13
// baseline (116.239 us; speedup 1.0000x reference)
//
#include <hip/hip_runtime.h>
#include <math.h>

constexpr int NQ  = 12;
constexpr int NL  = 4;
constexpr int BLK = 64;        // one wave per sample: zero barriers, zero LDS exchange
constexpr int R   = 64;        // amplitudes per thread
constexpr float PI_F = 3.14159265358979323846f;

// amp index i = (tid << 6) | r   (tid = lane 0..63)
//   bits 0..5  : register index r   (qubits 11..6)
//   bits 6..11 : lane bits t0..t5   (qubits 5..0)

typedef float c32 __attribute__((ext_vector_type(2)));   // (re, im) -> v_pk_* math

__device__ __forceinline__ c32 cmul(c32 a, c32 b) {
    c32 t = (c32){-a.y, a.y} * b.yx;
    return (c32){a.x, a.x} * b + t;
}
struct cg { c32 xx, ny; };
__device__ __forceinline__ cg mkg(c32 u) {
    cg g; g.xx = (c32){u.x, u.x}; g.ny = (c32){-u.y, u.y}; return g;
}
__device__ __forceinline__ c32 cmulg(cg g, c32 b) { return g.xx * b + g.ny * b.yx; }
__device__ __forceinline__ c32 cmadg(cg g, c32 b, c32 c) { return g.xx * b + (g.ny * b.yx + c); }

// ---------------- VALU lane-exchange primitives ----------------
// row_shr:N = lane i <- i-N, row_shl:N = lane i <- i+N (verified R5).
template<int CTRL>
__device__ __forceinline__ float dppmov(float v) {
    return __int_as_float(__builtin_amdgcn_mov_dpp(__float_as_int(v), CTRL, 0xF, 0xF, false));
}
__device__ __forceinline__ float dppx4(float v) {
    int s = __float_as_int(v);
    int o = __builtin_amdgcn_update_dpp(s, s, 0x104, 0xF, 0x5, false); // row_shl:4 -> banks 0,2
    o     = __builtin_amdgcn_update_dpp(o, s, 0x114, 0xF, 0xA, false); // row_shr:4 -> banks 1,3
    return __int_as_float(o);
}

#if __has_builtin(__builtin_amdgcn_permlane16_swap)
#define HAVE_PL16 1
#endif
#if __has_builtin(__builtin_amdgcn_permlane32_swap)
#define HAVE_PL32 1
#endif

template<int M>
__device__ __forceinline__ float lanex(float v, int tid) {
    if constexpr (M == 1)  return dppmov<0xB1>(v);        // quad_perm [1,0,3,2]
    else if constexpr (M == 2)  return dppmov<0x4E>(v);   // quad_perm [2,3,0,1]
    else if constexpr (M == 4)  return dppx4(v);
    else if constexpr (M == 8)  return dppmov<0x128>(v);  // row_ror:8
    else if constexpr (M == 16) {
#ifdef HAVE_PL16
        auto r = __builtin_amdgcn_permlane16_swap(__float_as_int(v), __float_as_int(v), false, false);
        return __int_as_float((tid & 16) ? r[0] : r[1]);
#else
        return __shfl_xor(v, 16, 64);
#endif
    } else { // M == 32
#ifdef HAVE_PL32
        auto r = __builtin_amdgcn_permlane32_swap(__float_as_int(v), __float_as_int(v), false, false);
        return __int_as_float((tid & 32) ? r[0] : r[1]);
#else
        return __shfl_xor(v, 32, 64);
#endif
    }
}
template<int M>
__device__ __forceinline__ c32 cx(c32 v, int tid) {
    return (c32){lanex<M>(v.x, tid), lanex<M>(v.y, tid)};
}

// ---- gate on a register bit P (pure FMA) ----
template<int P>
__device__ __forceinline__ void gate_reg(c32* v, const c32* u) {
    const cg g00 = mkg(u[0]), g01 = mkg(u[1]), g10 = mkg(u[2]), g11 = mkg(u[3]);
    #pragma unroll
    for (int r = 0; r < R; ++r)
        if (!(r & (1 << P))) {
            c32 a = v[r], b = v[r | (1 << P)];
            v[r]            = cmadg(g01, b, cmulg(g00, a));
            v[r | (1 << P)] = cmadg(g11, b, cmulg(g10, a));
        }
}

// ---- gate on a lane bit (DPP/permlane exchange) ----
template<int M>
__device__ __forceinline__ void gate_lane(c32* v, int tid, const c32* u) {
    const bool hi = tid & M;
    const c32 Ud = hi ? u[3] : u[0];
    const c32 Uo = hi ? u[2] : u[1];
    const cg gd = mkg(Ud), go = mkg(Uo);
    #pragma unroll
    for (int r = 0; r < R; ++r) {
        c32 o = cx<M>(v[r], tid);
        v[r] = cmadg(gd, v[r], cmulg(go, o));
    }
}

// ---- CNOT, ctrl+tgt both lane bits (exec-masked; verified R9) ----
template<int CM, int TM>
__device__ __forceinline__ void cnot_ll(c32* v, int tid) {
    if (tid & CM) {
        #pragma unroll
        for (int r = 0; r < R; ++r) v[r] = cx<TM>(v[r], tid);
    }
}

// ---- CNOT, ctrl+tgt both register bits ----
template<int PC, int PT>
__device__ __forceinline__ void cnot_rr(c32* v) {
    #pragma unroll
    for (int r = 0; r < R; ++r)
        if ((r & (1 << PC)) && !(r & (1 << PT))) {
            c32 t = v[r]; v[r] = v[r ^ (1 << PT)]; v[r ^ (1 << PT)] = t;
        }
}

__global__ __launch_bounds__(BLK, 1)
void qsim_kernel(const float* __restrict__ x,    // (B,12)
                 const float* __restrict__ w,    // (4,12,3)
                 const float* __restrict__ ent,  // (4,12)
                 float* __restrict__ out)        // (B,12)
{
    __shared__ c32 gmat[NL * NQ][4];   // 1.5 KB
    __shared__ c32 uenc[NQ][2];        // 192 B

    const int tid = threadIdx.x;       // 0..63
    const int b   = blockIdx.x;

    bool f = false;
    if (tid < NL * NQ) {
        float phi = w[tid * 3 + 0], th = w[tid * 3 + 1], om = w[tid * 3 + 2];
        float si, c;  sincosf(0.5f * th, &si, &c);
        float sa, ca; sincosf(0.5f * (phi + om), &sa, &ca);
        float sm, cm; sincosf(0.5f * (phi - om), &sm, &cm);
        gmat[tid][0] = (c32){ c  * ca, -c  * sa};
        gmat[tid][1] = (c32){-si * cm, -si * sm};
        gmat[tid][2] = (c32){ si * cm, -si * sm};
        gmat[tid][3] = (c32){ c  * ca,  c  * sa};
        f = ent[tid] > 0.5f;
    }
    const unsigned long long emv = __ballot(f);      // single wave: bits 0..47
    const unsigned em_lo = __builtin_amdgcn_readfirstlane((unsigned)emv);
    const unsigned em_hi = __builtin_amdgcn_readfirstlane((unsigned)(emv >> 32));
    const unsigned long long em = (((unsigned long long)em_hi) << 32) | em_lo;
    #define ENT(i) ((em >> (i)) & 1ull)

    if (tid < NQ) {
        float xv = x[b * NQ + tid];
        float si, c;  sincosf(0.5f * PI_F * xv, &si, &c);
        float zs, zc; sincosf(0.5f * PI_F * xv * xv, &zs, &zc);
        uenc[tid][0] = (c32){c  * zc, -c  * zs};
        uenc[tid][1] = (c32){si * zc,  si * zs};
    }
    __syncthreads();   // single-wave: cheap fence for LDS visibility

    // ---- encoded product state in registers ----
    // q0..q5 -> lane bits t5..t0 ; q6..q11 -> r bits 5..0
    c32 A = uenc[0][(tid >> 5) & 1];
    #pragma unroll
    for (int q = 1; q < 6; ++q) A = cmul(A, uenc[q][(tid >> (5 - q)) & 1]);
    c32 AU[4];
    #pragma unroll
    for (int k = 0; k < 4; ++k)
        AU[k] = cmul(A, cmul(uenc[6][k >> 1], uenc[7][k & 1]));
    c32 BC[16];
    #pragma unroll
    for (int j = 0; j < 16; ++j)
        BC[j] = cmul(cmul(uenc[8][(j >> 3) & 1], uenc[9][(j >> 2) & 1]),
                     cmul(uenc[10][(j >> 1) & 1], uenc[11][j & 1]));
    c32 v[R];
    #pragma unroll
    for (int r = 0; r < R; ++r) v[r] = cmul(AU[r >> 4], BC[r & 15]);

    // ---- layers: every gate is register/DPP; no barriers anywhere ----
    #pragma unroll 1
    for (int layer = 0; layer < NL; ++layer) {
        const int gb = layer * NQ;

        gate_lane<32>(v, tid, gmat[gb + 0]);   // q0  (bit11 = t5)
        gate_lane<16>(v, tid, gmat[gb + 1]);   // q1
        gate_lane< 8>(v, tid, gmat[gb + 2]);   // q2
        gate_lane< 4>(v, tid, gmat[gb + 3]);   // q3
        gate_lane< 2>(v, tid, gmat[gb + 4]);   // q4
        gate_lane< 1>(v, tid, gmat[gb + 5]);   // q5  (bit6 = t0)
        gate_reg<5>(v, gmat[gb + 6]);          // q6  (bit5 = r5)
        gate_reg<4>(v, gmat[gb + 7]);
        gate_reg<3>(v, gmat[gb + 8]);
        gate_reg<2>(v, gmat[gb + 9]);
        gate_reg<1>(v, gmat[gb + 10]);
        gate_reg<0>(v, gmat[gb + 11]);         // q11 (bit0 = r0)

        // ring CNOTs: ctrl bit (11-q), tgt bit (10-q); wrap q=11: (0,11)
        if (ENT(gb + 0)) cnot_ll<32, 16>(v, tid);   // (11,10)
        if (ENT(gb + 1)) cnot_ll<16,  8>(v, tid);   // (10,9)
        if (ENT(gb + 2)) cnot_ll< 8,  4>(v, tid);   // (9,8)
        if (ENT(gb + 3)) cnot_ll< 4,  2>(v, tid);   // (8,7)
        if (ENT(gb + 4)) cnot_ll< 2,  1>(v, tid);   // (7,6)
        if (ENT(gb + 5)) {                          // (6,5): ctrl lane t0, tgt reg r5
            const bool c_ = tid & 1;
            #pragma unroll
            for (int r = 0; r < 32; ++r) {
                c32 a = v[r], bb = v[r | 32];
                v[r]      = c_ ? bb : a;
                v[r | 32] = c_ ? a  : bb;
            }
        }
        if (ENT(gb + 6))  cnot_rr<5, 4>(v);         // (5,4)
        if (ENT(gb + 7))  cnot_rr<4, 3>(v);         // (4,3)
        if (ENT(gb + 8))  cnot_rr<3, 2>(v);         // (3,2)
        if (ENT(gb + 9))  cnot_rr<2, 1>(v);         // (2,1)
        if (ENT(gb + 10)) cnot_rr<1, 0>(v);         // (1,0)
        if (ENT(gb + 11)) {                         // (0,11): ctrl reg r0, tgt lane t5
            #pragma unroll
            for (int r = 1; r < R; r += 2) v[r] = cx<32>(v[r], tid);
        }
    }

    // ---- measurement ----
    float pr[R];
    #pragma unroll
    for (int r = 0; r < R; ++r) {
        c32 p = v[r] * v[r];
        pr[r] = p.x + p.y;
    }
    float S = 0.f;
    #pragma unroll
    for (int r = 0; r < R; ++r) S += pr[r];
    float T[6];
    #pragma unroll
    for (int pb = 0; pb < 6; ++pb) {
        float t = 0.f;
        #pragma unroll
        for (int r = 0; r < R; ++r) t += ((r >> pb) & 1) ? -pr[r] : pr[r];
        T[pb] = t;
    }

    float contrib[NQ];
    #pragma unroll
    for (int q = 0; q < 6; ++q) contrib[q] = ((tid >> (5 - q)) & 1) ? -S : S;
    contrib[6]  = T[5]; contrib[7]  = T[4]; contrib[8]  = T[3];
    contrib[9]  = T[2]; contrib[10] = T[1]; contrib[11] = T[0];

    // all-VALU butterfly: every lane ends with the full sums
    #pragma unroll
    for (int q = 0; q < NQ; ++q) {
        contrib[q] += lanex< 1>(contrib[q], tid);
        contrib[q] += lanex< 2>(contrib[q], tid);
        contrib[q] += lanex< 4>(contrib[q], tid);
        contrib[q] += lanex< 8>(contrib[q], tid);
        contrib[q] += lanex<16>(contrib[q], tid);
        contrib[q] += lanex<32>(contrib[q], tid);
    }
    if (tid == 0) {
        #pragma unroll
        for (int q = 0; q < NQ; ++q) out[b * NQ + q] = contrib[q];
    }
    #undef ENT
}

extern "C" void kernel_launch(void* const* d_in, const int* in_sizes, int n_in,
                              void* d_out, int out_size, void* d_ws, size_t ws_size,
                              hipStream_t stream) {
    const float* x   = (const float*)d_in[0];  // (B,12)
    const float* w   = (const float*)d_in[1];  // (4,12,3)
    const float* ent = (const float*)d_in[2];  // (4,12)
    float* out = (float*)d_out;
    const int B = in_sizes[0] / NQ;
    qsim_kernel<<<B, BLK, 0, stream>>>(x, w, ent, out);
}

// Round 14
// 78.702 us; speedup vs baseline: 1.4770x; 1.4770x over previous
//
#include <hip/hip_runtime.h>
#include <math.h>

constexpr int NQ  = 12;
constexpr int NS  = 1 << NQ;   // 4096 amplitudes
constexpr int NL  = 4;
constexpr int BLK = 256;
constexpr int R   = 16;        // amplitudes per thread (reg bits = amp bits 0..3)
constexpr float PI_F = 3.14159265358979323846f;

// amp index i = (tid << 4) | r
//   bits 0..3  : register index r
//   bits 4..9  : lane bits (tid bits 0..5)
//   bits 10..11: wave bits (tid bits 6..7)

typedef float c32 __attribute__((ext_vector_type(2)));   // (re, im) -> v_pk_* math

__device__ __forceinline__ c32 cmul(c32 a, c32 b) {
    c32 t = (c32){-a.y, a.y} * b.yx;
    return (c32){a.x, a.x} * b + t;
}
struct cg { c32 xx, ny; };
__device__ __forceinline__ cg mkg(c32 u) {
    cg g; g.xx = (c32){u.x, u.x}; g.ny = (c32){-u.y, u.y}; return g;
}
__device__ __forceinline__ c32 cmulg(cg g, c32 b) { return g.xx * b + g.ny * b.yx; }
__device__ __forceinline__ c32 cmadg(cg g, c32 b, c32 c) { return g.xx * b + (g.ny * b.yx + c); }

// ---------------- VALU lane-exchange primitives ----------------
// row_shr:N = lane i <- i-N, row_shl:N = lane i <- i+N (verified R5).
template<int CTRL>
__device__ __forceinline__ float dppmov(float v) {
    return __int_as_float(__builtin_amdgcn_mov_dpp(__float_as_int(v), CTRL, 0xF, 0xF, false));
}
__device__ __forceinline__ float dppx4(float v) {
    int s = __float_as_int(v);
    int o = __builtin_amdgcn_update_dpp(s, s, 0x104, 0xF, 0x5, false); // row_shl:4 -> banks 0,2
    o     = __builtin_amdgcn_update_dpp(o, s, 0x114, 0xF, 0xA, false); // row_shr:4 -> banks 1,3
    return __int_as_float(o);
}

#if __has_builtin(__builtin_amdgcn_permlane16_swap)
#define HAVE_PL16 1
#endif
#if __has_builtin(__builtin_amdgcn_permlane32_swap)
#define HAVE_PL32 1
#endif

template<int M>
__device__ __forceinline__ float lanex(float v, int tid) {
    if constexpr (M == 1)  return dppmov<0xB1>(v);        // quad_perm [1,0,3,2]
    else if constexpr (M == 2)  return dppmov<0x4E>(v);   // quad_perm [2,3,0,1]
    else if constexpr (M == 4)  return dppx4(v);
    else if constexpr (M == 8)  return dppmov<0x128>(v);  // row_ror:8
    else if constexpr (M == 16) {
#ifdef HAVE_PL16
        auto r = __builtin_amdgcn_permlane16_swap(__float_as_int(v), __float_as_int(v), false, false);
        return __int_as_float((tid & 16) ? r[0] : r[1]);
#else
        return __shfl_xor(v, 16, 64);
#endif
    } else { // M == 32
#ifdef HAVE_PL32
        auto r = __builtin_amdgcn_permlane32_swap(__float_as_int(v), __float_as_int(v), false, false);
        return __int_as_float((tid & 32) ? r[0] : r[1]);
#else
        return __shfl_xor(v, 32, 64);
#endif
    }
}
template<int M>
__device__ __forceinline__ c32 cx(c32 v, int tid) {
    return (c32){lanex<M>(v.x, tid), lanex<M>(v.y, tid)};
}

template<int P>
__device__ __forceinline__ void gate_reg(c32* v, const c32* u) {
    const cg g00 = mkg(u[0]), g01 = mkg(u[1]), g10 = mkg(u[2]), g11 = mkg(u[3]);
    #pragma unroll
    for (int r = 0; r < R; ++r)
        if (!(r & (1 << P))) {
            c32 a = v[r], b = v[r | (1 << P)];
            v[r]            = cmadg(g01, b, cmulg(g00, a));
            v[r | (1 << P)] = cmadg(g11, b, cmulg(g10, a));
        }
}

// phase-split lane gate: ALL exchanges first (16 independent DPP/permlane in
// flight), THEN all FMAs. Forces a wide ILP window the register-minimizing
// scheduler won't build on its own (R9 ran at VGPR=52 with serialized chains).
template<int M>
__device__ __forceinline__ void gate_lane(c32* v, int tid, const c32* u) {
    const bool hi = tid & M;
    const c32 Ud = hi ? u[3] : u[0];
    const c32 Uo = hi ? u[2] : u[1];
    const cg gd = mkg(Ud), go = mkg(Uo);
    c32 o[R];
    #pragma unroll
    for (int r = 0; r < R; ++r) o[r] = cx<M>(v[r], tid);
    #pragma unroll
    for (int r = 0; r < R; ++r) v[r] = cmadg(gd, v[r], cmulg(go, o[r]));
}

// exec-masked CNOT, phase-split the same way.
template<int CM, int TM>
__device__ __forceinline__ void cnot_ll(c32* v, int tid) {
    if (tid & CM) {
        c32 o[R];
        #pragma unroll
        for (int r = 0; r < R; ++r) o[r] = cx<TM>(v[r], tid);
        #pragma unroll
        for (int r = 0; r < R; ++r) v[r] = o[r];
    }
}

template<int PC, int PT>
__device__ __forceinline__ void cnot_rr(c32* v) {
    #pragma unroll
    for (int r = 0; r < R; ++r)
        if ((r & (1 << PC)) && !(r & (1 << PT))) {
            c32 t = v[r]; v[r] = v[r ^ (1 << PT)]; v[r ^ (1 << PT)] = t;
        }
}

__global__ __launch_bounds__(BLK, 1)
void qsim_kernel(const float* __restrict__ x,    // (B,12)
                 const float* __restrict__ w,    // (4,12,3)
                 const float* __restrict__ ent,  // (4,12)
                 float* __restrict__ out)        // (B,12)
{
    __shared__ c32  xbuf[NS];           // 32 KB cross-wave exchange
    __shared__ c32  gmat[NL * NQ][4];
    __shared__ c32  uenc[NQ][2];
    __shared__ int  entf[NL * NQ];
    __shared__ float redbuf[4 * NQ];

    const int tid = threadIdx.x;
    const int b   = blockIdx.x;

    if (tid < NL * NQ) {
        float phi = w[tid * 3 + 0], th = w[tid * 3 + 1], om = w[tid * 3 + 2];
        float s, c;   sincosf(0.5f * th, &s, &c);
        float sa, ca; sincosf(0.5f * (phi + om), &sa, &ca);
        float sm, cm; sincosf(0.5f * (phi - om), &sm, &cm);
        gmat[tid][0] = (c32){ c * ca, -c * sa};
        gmat[tid][1] = (c32){-s * cm, -s * sm};
        gmat[tid][2] = (c32){ s * cm, -s * sm};
        gmat[tid][3] = (c32){ c * ca,  c * sa};
        entf[tid] = ent[tid] > 0.5f;
    }
    if (tid >= 64 && tid < 64 + NQ) {
        int q = tid - 64;
        float xv = x[b * NQ + q];
        float s, c;   sincosf(0.5f * PI_F * xv, &s, &c);
        float zs, zc; sincosf(0.5f * PI_F * xv * xv, &zs, &zc);
        uenc[q][0] = (c32){c * zc, -c * zs};
        uenc[q][1] = (c32){s * zc,  s * zs};
    }
    __syncthreads();

    // ---- build encoded product state directly in registers ----
    c32 A = uenc[0][(tid >> 7) & 1];
    #pragma unroll
    for (int q = 1; q < 8; ++q) A = cmul(A, uenc[q][(tid >> (7 - q)) & 1]);
    c32 AP[4], PAB[4];
    #pragma unroll
    for (int j = 0; j < 4; ++j)
        AP[j] = cmul(A, cmul(uenc[8][j >> 1], uenc[9][j & 1]));
    #pragma unroll
    for (int k = 0; k < 4; ++k)
        PAB[k] = cmul(uenc[10][k >> 1], uenc[11][k & 1]);
    c32 v[R];
    #pragma unroll
    for (int r = 0; r < R; ++r) v[r] = cmul(AP[(r >> 2) & 3], PAB[r & 3]);

    const int lane_slot = tid & 63;
    const int g         = tid >> 6;   // quadrant = amp bits (11,10)

    // ---- layers ----
    #pragma unroll 1
    for (int layer = 0; layer < NL; ++layer) {
        const int gb = layer * NQ;

        // ===== fused 4x4 gate on amp bits (11,10) =====
        //   = Rot(bit11) ⊗ Rot(bit10), + this layer's CNOT(11,10) as row perm
        //   + prev layer's CNOT(0,11) as col perm on odd-r amplitudes.
        //   Phase-split: issue ALL 48 partner ds_reads, then all FMAs.
        {
            #pragma unroll
            for (int r = 0; r < R; ++r) xbuf[r * BLK + tid] = v[r];

            const c32* Ua = gmat[gb + 0];
            const c32* Ub = gmat[gb + 1];
            const int  gp = (entf[gb + 0] && (g & 2)) ? (g ^ 1) : g;  // CNOT(11,10) fold
            const int  ar = (gp >> 1) * 2, br = (gp & 1) * 2;
            // coefficient per source quadrant, indexed by xor-distance from g:
            c32 K0 = cmul(Ua[ar + ( g      >> 1)], Ub[br + ( g      & 1)]);  // own
            c32 K1 = cmul(Ua[ar + ((g ^ 1) >> 1)], Ub[br + ((g ^ 1) & 1)]);
            c32 K2 = cmul(Ua[ar + ((g ^ 2) >> 1)], Ub[br + ((g ^ 2) & 1)]);
            c32 K3 = cmul(Ua[ar + ((g ^ 3) >> 1)], Ub[br + ((g ^ 3) & 1)]);
            const bool pf = (layer > 0) && entf[gb - 1];              // prev CNOT(0,11) fold
            const cg gE0 = mkg(K0), gE1 = mkg(K1), gE2 = mkg(K2), gE3 = mkg(K3);
            const cg gO0 = mkg(pf ? K2 : K0), gO1 = mkg(pf ? K3 : K1);
            const cg gO2 = mkg(pf ? K0 : K2), gO3 = mkg(pf ? K1 : K3);

            const c32* p1 = xbuf + ((g ^ 1) << 6) + lane_slot;
            const c32* p2 = xbuf + ((g ^ 2) << 6) + lane_slot;
            const c32* p3 = xbuf + ((g ^ 3) << 6) + lane_slot;

            __syncthreads();
            c32 b1[R], b2[R], b3[R];
            #pragma unroll
            for (int r = 0; r < R; ++r) b1[r] = p1[r * BLK];
            #pragma unroll
            for (int r = 0; r < R; ++r) b2[r] = p2[r * BLK];
            #pragma unroll
            for (int r = 0; r < R; ++r) b3[r] = p3[r * BLK];
            #pragma unroll
            for (int r = 0; r < R; ++r) {
                c32 acc;
                if (r & 1) {
                    acc = cmulg(gO0, v[r]);
                    acc = cmadg(gO1, b1[r], acc);
                    acc = cmadg(gO2, b2[r], acc);
                    acc = cmadg(gO3, b3[r], acc);
                } else {
                    acc = cmulg(gE0, v[r]);
                    acc = cmadg(gE1, b1[r], acc);
                    acc = cmadg(gE2, b2[r], acc);
                    acc = cmadg(gE3, b3[r], acc);
                }
                v[r] = acc;
            }
            __syncthreads();
        }

        // ===== Rot gates on lane bits and reg bits =====
        gate_lane<32>(v, tid, gmat[gb + 2]);
        gate_lane<16>(v, tid, gmat[gb + 3]);
        gate_lane< 8>(v, tid, gmat[gb + 4]);
        gate_lane< 4>(v, tid, gmat[gb + 5]);
        gate_lane< 2>(v, tid, gmat[gb + 6]);
        gate_lane< 1>(v, tid, gmat[gb + 7]);
        gate_reg<3>(v, gmat[gb + 8]);
        gate_reg<2>(v, gmat[gb + 9]);
        gate_reg<1>(v, gmat[gb + 10]);
        gate_reg<0>(v, gmat[gb + 11]);

        // ===== CNOT chain (q=0 folded above; q=11 folded forward) =====
        if (entf[gb + 1] && (tid & 64)) {      // (10,9): ctrl wave bit6, tgt lane bit5
            c32 o[R];
            #pragma unroll
            for (int r = 0; r < R; ++r) o[r] = cx<32>(v[r], tid);
            #pragma unroll
            for (int r = 0; r < R; ++r) v[r] = o[r];
        }
        if (entf[gb + 2]) cnot_ll<32, 16>(v, tid);   // (9,8)
        if (entf[gb + 3]) cnot_ll<16,  8>(v, tid);   // (8,7)
        if (entf[gb + 4]) cnot_ll< 8,  4>(v, tid);   // (7,6)
        if (entf[gb + 5]) cnot_ll< 4,  2>(v, tid);   // (6,5)
        if (entf[gb + 6]) cnot_ll< 2,  1>(v, tid);   // (5,4)
        if (entf[gb + 7]) {                          // (4,3): ctrl lane bit0, tgt reg bit3
            const bool c_ = tid & 1;
            #pragma unroll
            for (int r = 0; r < 8; ++r) {
                c32 a = v[r], bb = v[r | 8];
                v[r]     = c_ ? bb : a;
                v[r | 8] = c_ ? a  : bb;
            }
        }
        if (entf[gb + 8])  cnot_rr<3, 2>(v);         // (3,2)
        if (entf[gb + 9])  cnot_rr<2, 1>(v);         // (2,1)
        if (entf[gb + 10]) cnot_rr<1, 0>(v);         // (1,0)
        // q=11 CNOT(0,11): folded into next fused gate, or into measurement
    }

    // ---- measurement; last layer's CNOT(0,11) folded into q0's sign ----
    const bool e011L = entf[(NL - 1) * NQ + 11];
    const int  t7    = (tid >> 7) & 1;

    float pr[R];
    #pragma unroll
    for (int r = 0; r < R; ++r) {
        c32 p = v[r] * v[r];
        pr[r] = p.x + p.y;
    }
    float S = 0.f, acc0 = 0.f;
    #pragma unroll
    for (int r = 0; r < R; ++r) {
        S += pr[r];
        const int s11 = t7 ^ (e011L & (r & 1));
        acc0 += s11 ? -pr[r] : pr[r];
    }
    float T[4];
    #pragma unroll
    for (int pb = 0; pb < 4; ++pb) {
        float t = 0.f;
        #pragma unroll
        for (int r = 0; r < R; ++r) t += ((r >> pb) & 1) ? -pr[r] : pr[r];
        T[pb] = t;
    }

    float contrib[NQ];
    contrib[0] = acc0;
    #pragma unroll
    for (int q = 1; q < 8; ++q) contrib[q] = ((tid >> (7 - q)) & 1) ? -S : S;
    contrib[8] = T[3]; contrib[9] = T[2]; contrib[10] = T[1]; contrib[11] = T[0];

    // all-VALU wave reduction (DPP/permlane), phase-split per step
    #pragma unroll
    for (int step = 0; step < 6; ++step) {
        float o[NQ];
        #pragma unroll
        for (int q = 0; q < NQ; ++q) {
            switch (step) {
                case 0: o[q] = lanex< 1>(contrib[q], tid); break;
                case 1: o[q] = lanex< 2>(contrib[q], tid); break;
                case 2: o[q] = lanex< 4>(contrib[q], tid); break;
                case 3: o[q] = lanex< 8>(contrib[q], tid); break;
                case 4: o[q] = lanex<16>(contrib[q], tid); break;
                default: o[q] = lanex<32>(contrib[q], tid); break;
            }
        }
        #pragma unroll
        for (int q = 0; q < NQ; ++q) contrib[q] += o[q];
    }
    if ((tid & 63) == 0) {
        const int wv = tid >> 6;
        #pragma unroll
        for (int q = 0; q < NQ; ++q) redbuf[wv * NQ + q] = contrib[q];
    }
    __syncthreads();
    if (tid < NQ)
        out[b * NQ + tid] = redbuf[tid] + redbuf[NQ + tid] + redbuf[2 * NQ + tid] + redbuf[3 * NQ + tid];
}

extern "C" void kernel_launch(void* const* d_in, const int* in_sizes, int n_in,
                              void* d_out, int out_size, void* d_ws, size_t ws_size,
                              hipStream_t stream) {
    const float* x   = (const float*)d_in[0];  // (B,12)
    const float* w   = (const float*)d_in[1];  // (4,12,3)
    const float* ent = (const float*)d_in[2];  // (4,12)
    float* out = (float*)d_out;
    const int B = in_sizes[0] / NQ;
    qsim_kernel<<<B, BLK, 0, stream>>>(x, w, ent, out);
}

// Round 15
// 78.144 us; speedup vs baseline: 1.4875x; 1.0071x over previous
//
#include <hip/hip_runtime.h>
#include <math.h>

constexpr int NQ  = 12;
constexpr int NS  = 1 << NQ;   // 4096 amplitudes
constexpr int NL  = 4;
constexpr int BLK = 256;
constexpr int R   = 16;        // amplitudes per thread (reg bits = amp bits 0..3)
constexpr float PI_F = 3.14159265358979323846f;

// amp index i = (tid << 4) | r
//   bits 0..3  : register index r
//   bits 4..9  : lane bits (tid bits 0..5)
//   bits 10..11: wave bits (tid bits 6..7)

typedef float c32 __attribute__((ext_vector_type(2)));   // (re, im) -> v_pk_* math

__device__ __forceinline__ c32 cmul(c32 a, c32 b) {
    c32 t = (c32){-a.y, a.y} * b.yx;
    return (c32){a.x, a.x} * b + t;
}
struct cg { c32 xx, ny; };
__device__ __forceinline__ cg mkg(c32 u) {
    cg g; g.xx = (c32){u.x, u.x}; g.ny = (c32){-u.y, u.y}; return g;
}
__device__ __forceinline__ c32 cmulg(cg g, c32 b) { return g.xx * b + g.ny * b.yx; }
__device__ __forceinline__ c32 cmadg(cg g, c32 b, c32 c) { return g.xx * b + (g.ny * b.yx + c); }

// hard scheduling fence: nothing moves across (forces the whole exchange
// batch live before any consumer -> wide ILP window, no chain serialization)
__device__ __forceinline__ void sfence() { __builtin_amdgcn_sched_barrier(0); }

// ---------------- VALU lane-exchange primitives ----------------
// row_shr:N = lane i <- i-N, row_shl:N = lane i <- i+N (verified R5).
template<int CTRL>
__device__ __forceinline__ float dppmov(float v) {
    return __int_as_float(__builtin_amdgcn_mov_dpp(__float_as_int(v), CTRL, 0xF, 0xF, false));
}
__device__ __forceinline__ float dppx4(float v) {
    int s = __float_as_int(v);
    int o = __builtin_amdgcn_update_dpp(s, s, 0x104, 0xF, 0x5, false); // row_shl:4 -> banks 0,2
    o     = __builtin_amdgcn_update_dpp(o, s, 0x114, 0xF, 0xA, false); // row_shr:4 -> banks 1,3
    return __int_as_float(o);
}

#if __has_builtin(__builtin_amdgcn_permlane16_swap)
#define HAVE_PL16 1
#endif
#if __has_builtin(__builtin_amdgcn_permlane32_swap)
#define HAVE_PL32 1
#endif

template<int M>
__device__ __forceinline__ float lanex(float v, int tid) {
    if constexpr (M == 1)  return dppmov<0xB1>(v);        // quad_perm [1,0,3,2]
    else if constexpr (M == 2)  return dppmov<0x4E>(v);   // quad_perm [2,3,0,1]
    else if constexpr (M == 4)  return dppx4(v);
    else if constexpr (M == 8)  return dppmov<0x128>(v);  // row_ror:8
    else if constexpr (M == 16) {
#ifdef HAVE_PL16
        auto r = __builtin_amdgcn_permlane16_swap(__float_as_int(v), __float_as_int(v), false, false);
        return __int_as_float((tid & 16) ? r[0] : r[1]);
#else
        return __shfl_xor(v, 16, 64);
#endif
    } else { // M == 32
#ifdef HAVE_PL32
        auto r = __builtin_amdgcn_permlane32_swap(__float_as_int(v), __float_as_int(v), false, false);
        return __int_as_float((tid & 32) ? r[0] : r[1]);
#else
        return __shfl_xor(v, 32, 64);
#endif
    }
}
template<int M>
__device__ __forceinline__ c32 cx(c32 v, int tid) {
    return (c32){lanex<M>(v.x, tid), lanex<M>(v.y, tid)};
}

template<int P>
__device__ __forceinline__ void gate_reg(c32* v, const c32* u) {
    const cg g00 = mkg(u[0]), g01 = mkg(u[1]), g10 = mkg(u[2]), g11 = mkg(u[3]);
    #pragma unroll
    for (int r = 0; r < R; ++r)
        if (!(r & (1 << P))) {
            c32 a = v[r], b = v[r | (1 << P)];
            v[r]            = cmadg(g01, b, cmulg(g00, a));
            v[r | (1 << P)] = cmadg(g11, b, cmulg(g10, a));
        }
}

// phase-split lane gate with a hard sched fence between phases: all 16
// exchanges are forced live (32 VGPRs) and issue back-to-back.
template<int M>
__device__ __forceinline__ void gate_lane(c32* v, int tid, const c32* u) {
    const bool hi = tid & M;
    const c32 Ud = hi ? u[3] : u[0];
    const c32 Uo = hi ? u[2] : u[1];
    const cg gd = mkg(Ud), go = mkg(Uo);
    c32 o[R];
    #pragma unroll
    for (int r = 0; r < R; ++r) o[r] = cx<M>(v[r], tid);
    sfence();
    #pragma unroll
    for (int r = 0; r < R; ++r) v[r] = cmadg(gd, v[r], cmulg(go, o[r]));
}

// exec-masked CNOT, phase-split + fence.
template<int CM, int TM>
__device__ __forceinline__ void cnot_ll(c32* v, int tid) {
    if (tid & CM) {
        c32 o[R];
        #pragma unroll
        for (int r = 0; r < R; ++r) o[r] = cx<TM>(v[r], tid);
        sfence();
        #pragma unroll
        for (int r = 0; r < R; ++r) v[r] = o[r];
    }
}

template<int PC, int PT>
__device__ __forceinline__ void cnot_rr(c32* v) {
    #pragma unroll
    for (int r = 0; r < R; ++r)
        if ((r & (1 << PC)) && !(r & (1 << PT))) {
            c32 t = v[r]; v[r] = v[r ^ (1 << PT)]; v[r ^ (1 << PT)] = t;
        }
}

__global__ __launch_bounds__(BLK, 1)
void qsim_kernel(const float* __restrict__ x,    // (B,12)
                 const float* __restrict__ w,    // (4,12,3)
                 const float* __restrict__ ent,  // (4,12)
                 float* __restrict__ out)        // (B,12)
{
    __shared__ c32  xbuf[NS];           // 32 KB cross-wave exchange
    __shared__ c32  gmat[NL * NQ][4];
    __shared__ c32  uenc[NQ][2];
    __shared__ int  entf[NL * NQ];
    __shared__ float redbuf[4 * NQ];

    const int tid = threadIdx.x;
    const int b   = blockIdx.x;

    if (tid < NL * NQ) {
        float phi = w[tid * 3 + 0], th = w[tid * 3 + 1], om = w[tid * 3 + 2];
        float s, c;   sincosf(0.5f * th, &s, &c);
        float sa, ca; sincosf(0.5f * (phi + om), &sa, &ca);
        float sm, cm; sincosf(0.5f * (phi - om), &sm, &cm);
        gmat[tid][0] = (c32){ c * ca, -c * sa};
        gmat[tid][1] = (c32){-s * cm, -s * sm};
        gmat[tid][2] = (c32){ s * cm, -s * sm};
        gmat[tid][3] = (c32){ c * ca,  c * sa};
        entf[tid] = ent[tid] > 0.5f;
    }
    if (tid >= 64 && tid < 64 + NQ) {
        int q = tid - 64;
        float xv = x[b * NQ + q];
        float s, c;   sincosf(0.5f * PI_F * xv, &s, &c);
        float zs, zc; sincosf(0.5f * PI_F * xv * xv, &zs, &zc);
        uenc[q][0] = (c32){c * zc, -c * zs};
        uenc[q][1] = (c32){s * zc,  s * zs};
    }
    __syncthreads();

    // ---- build encoded product state directly in registers ----
    c32 A = uenc[0][(tid >> 7) & 1];
    #pragma unroll
    for (int q = 1; q < 8; ++q) A = cmul(A, uenc[q][(tid >> (7 - q)) & 1]);
    c32 AP[4], PAB[4];
    #pragma unroll
    for (int j = 0; j < 4; ++j)
        AP[j] = cmul(A, cmul(uenc[8][j >> 1], uenc[9][j & 1]));
    #pragma unroll
    for (int k = 0; k < 4; ++k)
        PAB[k] = cmul(uenc[10][k >> 1], uenc[11][k & 1]);
    c32 v[R];
    #pragma unroll
    for (int r = 0; r < R; ++r) v[r] = cmul(AP[(r >> 2) & 3], PAB[r & 3]);

    const int lane_slot = tid & 63;
    const int g         = tid >> 6;   // quadrant = amp bits (11,10)

    // ---- layers ----
    #pragma unroll 1
    for (int layer = 0; layer < NL; ++layer) {
        const int gb = layer * NQ;

        // ===== fused 4x4 gate on amp bits (11,10) =====
        //   = Rot(bit11) ⊗ Rot(bit10), + this layer's CNOT(11,10) as row perm
        //   + prev layer's CNOT(0,11) as col perm on odd-r amplitudes.
        //   Phase-split + fences: all 48 partner ds_reads in flight, then FMAs.
        {
            #pragma unroll
            for (int r = 0; r < R; ++r) xbuf[r * BLK + tid] = v[r];

            const c32* Ua = gmat[gb + 0];
            const c32* Ub = gmat[gb + 1];
            const int  gp = (entf[gb + 0] && (g & 2)) ? (g ^ 1) : g;  // CNOT(11,10) fold
            const int  ar = (gp >> 1) * 2, br = (gp & 1) * 2;
            c32 K0 = cmul(Ua[ar + ( g      >> 1)], Ub[br + ( g      & 1)]);  // own
            c32 K1 = cmul(Ua[ar + ((g ^ 1) >> 1)], Ub[br + ((g ^ 1) & 1)]);
            c32 K2 = cmul(Ua[ar + ((g ^ 2) >> 1)], Ub[br + ((g ^ 2) & 1)]);
            c32 K3 = cmul(Ua[ar + ((g ^ 3) >> 1)], Ub[br + ((g ^ 3) & 1)]);
            const bool pf = (layer > 0) && entf[gb - 1];              // prev CNOT(0,11) fold
            const cg gE0 = mkg(K0), gE1 = mkg(K1), gE2 = mkg(K2), gE3 = mkg(K3);
            const cg gO0 = mkg(pf ? K2 : K0), gO1 = mkg(pf ? K3 : K1);
            const cg gO2 = mkg(pf ? K0 : K2), gO3 = mkg(pf ? K1 : K3);

            const c32* p1 = xbuf + ((g ^ 1) << 6) + lane_slot;
            const c32* p2 = xbuf + ((g ^ 2) << 6) + lane_slot;
            const c32* p3 = xbuf + ((g ^ 3) << 6) + lane_slot;

            __syncthreads();
            c32 b1[R], b2[R], b3[R];
            #pragma unroll
            for (int r = 0; r < R; ++r) b1[r] = p1[r * BLK];
            #pragma unroll
            for (int r = 0; r < R; ++r) b2[r] = p2[r * BLK];
            #pragma unroll
            for (int r = 0; r < R; ++r) b3[r] = p3[r * BLK];
            sfence();
            #pragma unroll
            for (int r = 0; r < R; ++r) {
                c32 acc;
                if (r & 1) {
                    acc = cmulg(gO0, v[r]);
                    acc = cmadg(gO1, b1[r], acc);
                    acc = cmadg(gO2, b2[r], acc);
                    acc = cmadg(gO3, b3[r], acc);
                } else {
                    acc = cmulg(gE0, v[r]);
                    acc = cmadg(gE1, b1[r], acc);
                    acc = cmadg(gE2, b2[r], acc);
                    acc = cmadg(gE3, b3[r], acc);
                }
                v[r] = acc;
            }
            __syncthreads();
        }

        // ===== Rot gates on lane bits and reg bits =====
        gate_lane<32>(v, tid, gmat[gb + 2]);
        gate_lane<16>(v, tid, gmat[gb + 3]);
        gate_lane< 8>(v, tid, gmat[gb + 4]);
        gate_lane< 4>(v, tid, gmat[gb + 5]);
        gate_lane< 2>(v, tid, gmat[gb + 6]);
        gate_lane< 1>(v, tid, gmat[gb + 7]);
        gate_reg<3>(v, gmat[gb + 8]);
        gate_reg<2>(v, gmat[gb + 9]);
        gate_reg<1>(v, gmat[gb + 10]);
        gate_reg<0>(v, gmat[gb + 11]);

        // ===== CNOT chain (q=0 folded above; q=11 folded forward) =====
        if (entf[gb + 1] && (tid & 64)) {      // (10,9): ctrl wave bit6, tgt lane bit5
            c32 o[R];
            #pragma unroll
            for (int r = 0; r < R; ++r) o[r] = cx<32>(v[r], tid);
            sfence();
            #pragma unroll
            for (int r = 0; r < R; ++r) v[r] = o[r];
        }
        if (entf[gb + 2]) cnot_ll<32, 16>(v, tid);   // (9,8)
        if (entf[gb + 3]) cnot_ll<16,  8>(v, tid);   // (8,7)
        if (entf[gb + 4]) cnot_ll< 8,  4>(v, tid);   // (7,6)
        if (entf[gb + 5]) cnot_ll< 4,  2>(v, tid);   // (6,5)
        if (entf[gb + 6]) cnot_ll< 2,  1>(v, tid);   // (5,4)
        if (entf[gb + 7]) {                          // (4,3): ctrl lane bit0, tgt reg bit3
            const bool c_ = tid & 1;
            #pragma unroll
            for (int r = 0; r < 8; ++r) {
                c32 a = v[r], bb = v[r | 8];
                v[r]     = c_ ? bb : a;
                v[r | 8] = c_ ? a  : bb;
            }
        }
        if (entf[gb + 8])  cnot_rr<3, 2>(v);         // (3,2)
        if (entf[gb + 9])  cnot_rr<2, 1>(v);         // (2,1)
        if (entf[gb + 10]) cnot_rr<1, 0>(v);         // (1,0)
        // q=11 CNOT(0,11): folded into next fused gate, or into measurement
    }

    // ---- measurement; last layer's CNOT(0,11) folded into q0's sign ----
    const bool e011L = entf[(NL - 1) * NQ + 11];
    const int  t7    = (tid >> 7) & 1;

    float pr[R];
    #pragma unroll
    for (int r = 0; r < R; ++r) {
        c32 p = v[r] * v[r];
        pr[r] = p.x + p.y;
    }
    float S = 0.f, acc0 = 0.f;
    #pragma unroll
    for (int r = 0; r < R; ++r) {
        S += pr[r];
        const int s11 = t7 ^ (e011L & (r & 1));
        acc0 += s11 ? -pr[r] : pr[r];
    }
    float T[4];
    #pragma unroll
    for (int pb = 0; pb < 4; ++pb) {
        float t = 0.f;
        #pragma unroll
        for (int r = 0; r < R; ++r) t += ((r >> pb) & 1) ? -pr[r] : pr[r];
        T[pb] = t;
    }

    float contrib[NQ];
    contrib[0] = acc0;
    #pragma unroll
    for (int q = 1; q < 8; ++q) contrib[q] = ((tid >> (7 - q)) & 1) ? -S : S;
    contrib[8] = T[3]; contrib[9] = T[2]; contrib[10] = T[1]; contrib[11] = T[0];

    // all-VALU wave reduction (DPP/permlane), phase-split per step
    #pragma unroll
    for (int step = 0; step < 6; ++step) {
        float o[NQ];
        #pragma unroll
        for (int q = 0; q < NQ; ++q) {
            switch (step) {
                case 0: o[q] = lanex< 1>(contrib[q], tid); break;
                case 1: o[q] = lanex< 2>(contrib[q], tid); break;
                case 2: o[q] = lanex< 4>(contrib[q], tid); break;
                case 3: o[q] = lanex< 8>(contrib[q], tid); break;
                case 4: o[q] = lanex<16>(contrib[q], tid); break;
                default: o[q] = lanex<32>(contrib[q], tid); break;
            }
        }
        #pragma unroll
        for (int q = 0; q < NQ; ++q) contrib[q] += o[q];
    }
    if ((tid & 63) == 0) {
        const int wv = tid >> 6;
        #pragma unroll
        for (int q = 0; q < NQ; ++q) redbuf[wv * NQ + q] = contrib[q];
    }
    __syncthreads();
    if (tid < NQ)
        out[b * NQ + tid] = redbuf[tid] + redbuf[NQ + tid] + redbuf[2 * NQ + tid] + redbuf[3 * NQ + tid];
}

extern "C" void kernel_launch(void* const* d_in, const int* in_sizes, int n_in,
                              void* d_out, int out_size, void* d_ws, size_t ws_size,
                              hipStream_t stream) {
    const float* x   = (const float*)d_in[0];  // (B,12)
    const float* w   = (const float*)d_in[1];  // (4,12,3)
    const float* ent = (const float*)d_in[2];  // (4,12)
    float* out = (float*)d_out;
    const int B = in_sizes[0] / NQ;
    qsim_kernel<<<B, BLK, 0, stream>>>(x, w, ent, out);
}